// Round 1
// baseline (2833.998 us; speedup 1.0000x reference)
//
#include <hip/hip_runtime.h>
#include <hip/hip_bf16.h>

#define DIM 256
#define HEADS 4
#define NEG_SLOPE 0.01f

// ---- sortable-uint encoding for float atomicMax ----
__device__ __forceinline__ unsigned f2sort(float f) {
    unsigned u = __float_as_uint(f);
    return (u & 0x80000000u) ? ~u : (u | 0x80000000u);
}
__device__ __forceinline__ float sort2f(unsigned s) {
    return (s & 0x80000000u) ? __uint_as_float(s & 0x7fffffffu)
                             : __uint_as_float(~s);
}

// K1: beta[j,h] = sum_{d<64} x_edge[j, h*64+d] * weight[h, d]
// one wave per edge row; lane l covers 4 floats, head = l/16
__global__ __launch_bounds__(256) void beta_kernel(const float* __restrict__ xe,
                                                   const float* __restrict__ weight,
                                                   float* __restrict__ beta, int NE) {
    int wid = blockIdx.x * 4 + (threadIdx.x >> 6);
    if (wid >= NE) return;
    int lane = threadIdx.x & 63;
    int h = lane >> 4;
    float4 v = *reinterpret_cast<const float4*>(xe + (size_t)wid * DIM + lane * 4);
    float4 w = *reinterpret_cast<const float4*>(weight + h * 128 + (lane & 15) * 4);
    float p = v.x * w.x + v.y * w.y + v.z * w.z + v.w * w.w;
    p += __shfl_xor(p, 1);
    p += __shfl_xor(p, 2);
    p += __shfl_xor(p, 4);
    p += __shfl_xor(p, 8);
    if ((lane & 15) == 0) beta[(size_t)wid * 4 + h] = p;
}

// K2: xq = x_q @ w_q (fp32), fused gamma[e,h] = sum_{d<64} xq[e,h*64+d]*weight[h,64+d]
// block 256 threads computes 64 rows x 256 cols. thread (tc=t&15, tr=t>>4)
// owns rows tr*4..+3, cols tc*4 + 64*j (+i), j<4, i<4.
#define BM 64
#define BK 32
__global__ __launch_bounds__(256) void gemm_gamma_kernel(const float* __restrict__ A,
                                                         const float* __restrict__ B,
                                                         const float* __restrict__ weight,
                                                         float* __restrict__ xq_out,
                                                         float* __restrict__ gamma, int NQ) {
    __shared__ float Asm[BK][68];   // transposed: Asm[k][row], pad 68 keeps 16B align + 2-way max
    __shared__ float Bsm[BK][260];  // Bsm[k][col]
    const int t = threadIdx.x;
    const int tc = t & 15;
    const int tr = t >> 4;
    const long brow = (long)blockIdx.x * BM;

    float acc[4][16];
#pragma unroll
    for (int r = 0; r < 4; ++r)
#pragma unroll
        for (int c = 0; c < 16; ++c) acc[r][c] = 0.f;

    for (int k0 = 0; k0 < DIM; k0 += BK) {
        // stage A tile (BM x BK), transposed into LDS
#pragma unroll
        for (int i = 0; i < 2; ++i) {
            int idx = t + i * 256;
            int r = idx >> 3, c4 = idx & 7;
            long grow = brow + r;
            if (grow > (long)NQ - 1) grow = NQ - 1;
            float4 v = *reinterpret_cast<const float4*>(A + grow * DIM + k0 + c4 * 4);
            Asm[c4 * 4 + 0][r] = v.x;
            Asm[c4 * 4 + 1][r] = v.y;
            Asm[c4 * 4 + 2][r] = v.z;
            Asm[c4 * 4 + 3][r] = v.w;
        }
        // stage B tile (BK x 256)
#pragma unroll
        for (int i = 0; i < 8; ++i) {
            int idx = t + i * 256;
            int k = idx >> 6, c4 = idx & 63;
            float4 v = *reinterpret_cast<const float4*>(B + (size_t)(k0 + k) * DIM + c4 * 4);
            *reinterpret_cast<float4*>(&Bsm[k][c4 * 4]) = v;
        }
        __syncthreads();
#pragma unroll 8
        for (int kk = 0; kk < BK; ++kk) {
            float4 av = *reinterpret_cast<const float4*>(&Asm[kk][tr * 4]);
            float ar[4] = {av.x, av.y, av.z, av.w};
#pragma unroll
            for (int j = 0; j < 4; ++j) {
                float4 bv = *reinterpret_cast<const float4*>(&Bsm[kk][tc * 4 + 64 * j]);
                float br[4] = {bv.x, bv.y, bv.z, bv.w};
#pragma unroll
                for (int r = 0; r < 4; ++r)
#pragma unroll
                    for (int i = 0; i < 4; ++i)
                        acc[r][j * 4 + i] = fmaf(ar[r], br[i], acc[r][j * 4 + i]);
            }
        }
        __syncthreads();
    }

    // epilogue: store xq rows + fused gamma (per-head dot with weight[h,64:128])
#pragma unroll
    for (int r = 0; r < 4; ++r) {
        long grow = brow + tr * 4 + r;
        bool ok = grow < NQ;
#pragma unroll
        for (int j = 0; j < 4; ++j) {
            if (ok) {
                float4 v = make_float4(acc[r][j * 4 + 0], acc[r][j * 4 + 1],
                                       acc[r][j * 4 + 2], acc[r][j * 4 + 3]);
                *reinterpret_cast<float4*>(xq_out + grow * DIM + j * 64 + tc * 4) = v;
            }
            float4 w = *reinterpret_cast<const float4*>(weight + j * 128 + 64 + tc * 4);
            float p = acc[r][j * 4 + 0] * w.x + acc[r][j * 4 + 1] * w.y +
                      acc[r][j * 4 + 2] * w.z + acc[r][j * 4 + 3] * w.w;
            p += __shfl_xor(p, 1);
            p += __shfl_xor(p, 2);
            p += __shfl_xor(p, 4);
            p += __shfl_xor(p, 8);
            if (ok && tc == 0) gamma[grow * 4 + j] = p;
        }
    }
}

// K3: logit = leaky_relu(beta[eid] + gamma); atomicMax into segmax (sortable uint)
__global__ __launch_bounds__(256) void logits_kernel(const float* __restrict__ beta,
                                                     const float* __restrict__ gamma,
                                                     const int* __restrict__ eids,
                                                     float* __restrict__ logit,
                                                     unsigned* __restrict__ segmax, int NQ) {
    int e = blockIdx.x * blockDim.x + threadIdx.x;
    if (e >= NQ) return;
    int j = eids[e];
    float4 g = *reinterpret_cast<const float4*>(gamma + (size_t)e * 4);
    float4 b = *reinterpret_cast<const float4*>(beta + (size_t)j * 4);
    float l[4] = {b.x + g.x, b.y + g.y, b.z + g.z, b.w + g.w};
#pragma unroll
    for (int h = 0; h < 4; ++h) {
        l[h] = l[h] > 0.f ? l[h] : NEG_SLOPE * l[h];
        atomicMax(&segmax[(size_t)j * 4 + h], f2sort(l[h]));
    }
    *reinterpret_cast<float4*>(logit + (size_t)e * 4) = make_float4(l[0], l[1], l[2], l[3]);
}

// K4: ex = exp(logit - segmax[eid]); atomicAdd into segsum. ex overwrites logit buffer.
__global__ __launch_bounds__(256) void exp_kernel(float* __restrict__ logit,
                                                  const int* __restrict__ eids,
                                                  const unsigned* __restrict__ segmax,
                                                  float* __restrict__ segsum, int NQ) {
    int e = blockIdx.x * blockDim.x + threadIdx.x;
    if (e >= NQ) return;
    int j = eids[e];
    float4 l = *reinterpret_cast<const float4*>(logit + (size_t)e * 4);
    uint4 m = *reinterpret_cast<const uint4*>(segmax + (size_t)j * 4);
    float ex[4] = {__expf(l.x - sort2f(m.x)), __expf(l.y - sort2f(m.y)),
                   __expf(l.z - sort2f(m.z)), __expf(l.w - sort2f(m.w))};
    *reinterpret_cast<float4*>(logit + (size_t)e * 4) = make_float4(ex[0], ex[1], ex[2], ex[3]);
#pragma unroll
    for (int h = 0; h < 4; ++h) atomicAdd(&segsum[(size_t)j * 4 + h], ex[h]);
}

// K5: out[eid, :] += (ex/(segsum+eps))[h] * xq[e, :]  — one wave per qualifier
__global__ __launch_bounds__(256) void scatter_kernel(const float* __restrict__ ex,
                                                      const float* __restrict__ segsum,
                                                      const int* __restrict__ eids,
                                                      const float* __restrict__ xq,
                                                      float* __restrict__ out, int NQ) {
    int wid = blockIdx.x * 4 + (threadIdx.x >> 6);
    if (wid >= NQ) return;
    int lane = threadIdx.x & 63;
    int h = lane >> 4;
    int j = eids[wid];
    float w = ex[(size_t)wid * 4 + h] / (segsum[(size_t)j * 4 + h] + 1e-16f);
    float4 v = *reinterpret_cast<const float4*>(xq + (size_t)wid * DIM + lane * 4);
    float* o = out + (size_t)j * DIM + lane * 4;
    atomicAdd(o + 0, w * v.x);
    atomicAdd(o + 1, w * v.y);
    atomicAdd(o + 2, w * v.z);
    atomicAdd(o + 3, w * v.w);
}

extern "C" void kernel_launch(void* const* d_in, const int* in_sizes, int n_in,
                              void* d_out, int out_size, void* d_ws, size_t ws_size,
                              hipStream_t stream) {
    (void)n_in; (void)out_size; (void)ws_size;
    const float* x_q    = (const float*)d_in[0];
    const float* x_edge = (const float*)d_in[1];
    const float* w_q    = (const float*)d_in[2];
    const float* weight = (const float*)d_in[3];
    const int*   eids   = (const int*)d_in[4];
    const int NQ = in_sizes[0] / DIM;   // 500000
    const int NE = in_sizes[1] / DIM;   // 250000
    float* out = (float*)d_out;

    // workspace layout
    float*    xq     = (float*)d_ws;                    // NQ*256
    float*    gamma  = xq + (size_t)NQ * DIM;           // NQ*4
    float*    logit  = gamma + (size_t)NQ * 4;          // NQ*4 (becomes ex)
    float*    beta   = logit + (size_t)NQ * 4;          // NE*4
    unsigned* segmax = (unsigned*)(beta + (size_t)NE * 4); // NE*4
    float*    segsum = (float*)(segmax + (size_t)NE * 4);  // NE*4

    hipMemsetAsync(out, 0, (size_t)NE * DIM * sizeof(float), stream);
    hipMemsetAsync(segmax, 0, (size_t)NE * 4 * sizeof(unsigned), stream);
    hipMemsetAsync(segsum, 0, (size_t)NE * 4 * sizeof(float), stream);

    beta_kernel<<<(NE + 3) / 4, 256, 0, stream>>>(x_edge, weight, beta, NE);
    gemm_gamma_kernel<<<(NQ + BM - 1) / BM, 256, 0, stream>>>(x_q, w_q, weight, xq, gamma, NQ);
    logits_kernel<<<(NQ + 255) / 256, 256, 0, stream>>>(beta, gamma, eids, logit, segmax, NQ);
    exp_kernel<<<(NQ + 255) / 256, 256, 0, stream>>>(logit, eids, segmax, segsum, NQ);
    scatter_kernel<<<(NQ + 3) / 4, 256, 0, stream>>>(logit, segsum, eids, xq, out, NQ);
}

// Round 2
// 1302.894 us; speedup vs baseline: 2.1752x; 2.1752x over previous
//
#include <hip/hip_runtime.h>
#include <hip/hip_bf16.h>

#define DIM 256
#define HEADS 4
#define NEG_SLOPE 0.01f

// ---- sortable-uint encoding for float atomicMax ----
__device__ __forceinline__ unsigned f2sort(float f) {
    unsigned u = __float_as_uint(f);
    return (u & 0x80000000u) ? ~u : (u | 0x80000000u);
}
__device__ __forceinline__ float sort2f(unsigned s) {
    return (s & 0x80000000u) ? __uint_as_float(s & 0x7fffffffu)
                             : __uint_as_float(~s);
}

// K1: beta[j,h] = sum_{d<64} x_edge[j, h*64+d] * weight[h, d]
__global__ __launch_bounds__(256) void beta_kernel(const float* __restrict__ xe,
                                                   const float* __restrict__ weight,
                                                   float* __restrict__ beta, int NE) {
    int wid = blockIdx.x * 4 + (threadIdx.x >> 6);
    if (wid >= NE) return;
    int lane = threadIdx.x & 63;
    int h = lane >> 4;
    float4 v = *reinterpret_cast<const float4*>(xe + (size_t)wid * DIM + lane * 4);
    float4 w = *reinterpret_cast<const float4*>(weight + h * 128 + (lane & 15) * 4);
    float p = v.x * w.x + v.y * w.y + v.z * w.z + v.w * w.w;
    p += __shfl_xor(p, 1);
    p += __shfl_xor(p, 2);
    p += __shfl_xor(p, 4);
    p += __shfl_xor(p, 8);
    if ((lane & 15) == 0) beta[(size_t)wid * 4 + h] = p;
}

// K2: xq = x_q @ w_q (fp32), fused gamma[e,h] = sum_{d<64} xq[e,h*64+d]*weight[h,64+d]
#define BM 64
#define BK 32
__global__ __launch_bounds__(256) void gemm_gamma_kernel(const float* __restrict__ A,
                                                         const float* __restrict__ B,
                                                         const float* __restrict__ weight,
                                                         float* __restrict__ xq_out,
                                                         float* __restrict__ gamma, int NQ) {
    __shared__ float Asm[BK][68];
    __shared__ float Bsm[BK][260];
    const int t = threadIdx.x;
    const int tc = t & 15;
    const int tr = t >> 4;
    const long brow = (long)blockIdx.x * BM;

    float acc[4][16];
#pragma unroll
    for (int r = 0; r < 4; ++r)
#pragma unroll
        for (int c = 0; c < 16; ++c) acc[r][c] = 0.f;

    for (int k0 = 0; k0 < DIM; k0 += BK) {
#pragma unroll
        for (int i = 0; i < 2; ++i) {
            int idx = t + i * 256;
            int r = idx >> 3, c4 = idx & 7;
            long grow = brow + r;
            if (grow > (long)NQ - 1) grow = NQ - 1;
            float4 v = *reinterpret_cast<const float4*>(A + grow * DIM + k0 + c4 * 4);
            Asm[c4 * 4 + 0][r] = v.x;
            Asm[c4 * 4 + 1][r] = v.y;
            Asm[c4 * 4 + 2][r] = v.z;
            Asm[c4 * 4 + 3][r] = v.w;
        }
#pragma unroll
        for (int i = 0; i < 8; ++i) {
            int idx = t + i * 256;
            int k = idx >> 6, c4 = idx & 63;
            float4 v = *reinterpret_cast<const float4*>(B + (size_t)(k0 + k) * DIM + c4 * 4);
            *reinterpret_cast<float4*>(&Bsm[k][c4 * 4]) = v;
        }
        __syncthreads();
#pragma unroll 8
        for (int kk = 0; kk < BK; ++kk) {
            float4 av = *reinterpret_cast<const float4*>(&Asm[kk][tr * 4]);
            float ar[4] = {av.x, av.y, av.z, av.w};
#pragma unroll
            for (int j = 0; j < 4; ++j) {
                float4 bv = *reinterpret_cast<const float4*>(&Bsm[kk][tc * 4 + 64 * j]);
                float br[4] = {bv.x, bv.y, bv.z, bv.w};
#pragma unroll
                for (int r = 0; r < 4; ++r)
#pragma unroll
                    for (int i = 0; i < 4; ++i)
                        acc[r][j * 4 + i] = fmaf(ar[r], br[i], acc[r][j * 4 + i]);
            }
        }
        __syncthreads();
    }

#pragma unroll
    for (int r = 0; r < 4; ++r) {
        long grow = brow + tr * 4 + r;
        bool ok = grow < NQ;
#pragma unroll
        for (int j = 0; j < 4; ++j) {
            if (ok) {
                float4 v = make_float4(acc[r][j * 4 + 0], acc[r][j * 4 + 1],
                                       acc[r][j * 4 + 2], acc[r][j * 4 + 3]);
                *reinterpret_cast<float4*>(xq_out + grow * DIM + j * 64 + tc * 4) = v;
            }
            float4 w = *reinterpret_cast<const float4*>(weight + j * 128 + 64 + tc * 4);
            float p = acc[r][j * 4 + 0] * w.x + acc[r][j * 4 + 1] * w.y +
                      acc[r][j * 4 + 2] * w.z + acc[r][j * 4 + 3] * w.w;
            p += __shfl_xor(p, 1);
            p += __shfl_xor(p, 2);
            p += __shfl_xor(p, 4);
            p += __shfl_xor(p, 8);
            if (ok && tc == 0) gamma[grow * 4 + j] = p;
        }
    }
}

// K3: logit = leaky_relu(beta[eid] + gamma); atomicMax into segmax; also histogram counts
__global__ __launch_bounds__(256) void logits_kernel(const float* __restrict__ beta,
                                                     const float* __restrict__ gamma,
                                                     const int* __restrict__ eids,
                                                     float* __restrict__ logit,
                                                     unsigned* __restrict__ segmax,
                                                     unsigned* __restrict__ counts, int NQ) {
    int e = blockIdx.x * blockDim.x + threadIdx.x;
    if (e >= NQ) return;
    int j = eids[e];
    float4 g = *reinterpret_cast<const float4*>(gamma + (size_t)e * 4);
    float4 b = *reinterpret_cast<const float4*>(beta + (size_t)j * 4);
    float l[4] = {b.x + g.x, b.y + g.y, b.z + g.z, b.w + g.w};
#pragma unroll
    for (int h = 0; h < 4; ++h) {
        l[h] = l[h] > 0.f ? l[h] : NEG_SLOPE * l[h];
        atomicMax(&segmax[(size_t)j * 4 + h], f2sort(l[h]));
    }
    atomicAdd(&counts[j], 1u);
    *reinterpret_cast<float4*>(logit + (size_t)e * 4) = make_float4(l[0], l[1], l[2], l[3]);
}

// K4: ex = exp(logit - segmax[eid]); atomicAdd into segsum (in-place over logit)
__global__ __launch_bounds__(256) void exp_kernel(float* __restrict__ logit,
                                                  const int* __restrict__ eids,
                                                  const unsigned* __restrict__ segmax,
                                                  float* __restrict__ segsum, int NQ) {
    int e = blockIdx.x * blockDim.x + threadIdx.x;
    if (e >= NQ) return;
    int j = eids[e];
    float4 l = *reinterpret_cast<const float4*>(logit + (size_t)e * 4);
    uint4 m = *reinterpret_cast<const uint4*>(segmax + (size_t)j * 4);
    float ex[4] = {__expf(l.x - sort2f(m.x)), __expf(l.y - sort2f(m.y)),
                   __expf(l.z - sort2f(m.z)), __expf(l.w - sort2f(m.w))};
    *reinterpret_cast<float4*>(logit + (size_t)e * 4) = make_float4(ex[0], ex[1], ex[2], ex[3]);
#pragma unroll
    for (int h = 0; h < 4; ++h) atomicAdd(&segsum[(size_t)j * 4 + h], ex[h]);
}

// ---- CSR build: exclusive scan of counts ----
// scan1: per-block (1024 elems) local exclusive scan + block total
__global__ __launch_bounds__(256) void scan1_kernel(const unsigned* __restrict__ counts,
                                                    unsigned* __restrict__ offs,
                                                    unsigned* __restrict__ blocksums, int NE) {
    __shared__ unsigned s[256];
    int t = threadIdx.x;
    int base = blockIdx.x * 1024 + t * 4;
    unsigned v[4], sum = 0;
#pragma unroll
    for (int i = 0; i < 4; ++i) {
        v[i] = (base + i < NE) ? counts[base + i] : 0u;
        sum += v[i];
    }
    s[t] = sum;
    __syncthreads();
    // inclusive Hillis-Steele over 256
    for (int off = 1; off < 256; off <<= 1) {
        unsigned y = (t >= off) ? s[t - off] : 0u;
        __syncthreads();
        s[t] += y;
        __syncthreads();
    }
    unsigned excl = s[t] - sum;
#pragma unroll
    for (int i = 0; i < 4; ++i) {
        if (base + i < NE) offs[base + i] = excl;
        excl += v[i];
    }
    if (t == 255) blocksums[blockIdx.x] = s[255];
}

// scan2: single block scans blocksums (<=256) exclusively in place
__global__ __launch_bounds__(256) void scan2_kernel(unsigned* __restrict__ blocksums, int NB) {
    __shared__ unsigned s[256];
    int t = threadIdx.x;
    unsigned v = (t < NB) ? blocksums[t] : 0u;
    s[t] = v;
    __syncthreads();
    for (int off = 1; off < 256; off <<= 1) {
        unsigned y = (t >= off) ? s[t - off] : 0u;
        __syncthreads();
        s[t] += y;
        __syncthreads();
    }
    if (t < NB) blocksums[t] = s[t] - v;
}

// scan3: add block offset; also init cursor
__global__ __launch_bounds__(256) void scan3_kernel(unsigned* __restrict__ offs,
                                                    const unsigned* __restrict__ blocksums,
                                                    unsigned* __restrict__ cursor, int NE) {
    int t = threadIdx.x;
    int base = blockIdx.x * 1024 + t * 4;
    unsigned add = blocksums[blockIdx.x];
#pragma unroll
    for (int i = 0; i < 4; ++i) {
        if (base + i < NE) {
            unsigned o = offs[base + i] + add;
            offs[base + i] = o;
            cursor[base + i] = o;
        }
    }
}

// fill: qlist[cursor[j]++] = e
__global__ __launch_bounds__(256) void fill_kernel(const int* __restrict__ eids,
                                                   unsigned* __restrict__ cursor,
                                                   int* __restrict__ qlist, int NQ) {
    int e = blockIdx.x * blockDim.x + threadIdx.x;
    if (e >= NQ) return;
    int j = eids[e];
    unsigned pos = atomicAdd(&cursor[j], 1u);
    qlist[pos] = e;
}

// gather: out[j,:] = sum_{q in seg(j)} (ex[q,h]/(segsum[j,h]+eps)) * xq[q,:]
__global__ __launch_bounds__(256) void gather_kernel(const float* __restrict__ ex,
                                                     const float* __restrict__ segsum,
                                                     const unsigned* __restrict__ offs,
                                                     const unsigned* __restrict__ counts,
                                                     const int* __restrict__ qlist,
                                                     const float* __restrict__ xq,
                                                     float* __restrict__ out, int NE) {
    int j = blockIdx.x * 4 + (threadIdx.x >> 6);
    if (j >= NE) return;
    int lane = threadIdx.x & 63;
    int h = lane >> 4;
    unsigned beg = offs[j];
    unsigned n = counts[j];
    float inv = 1.0f / (segsum[(size_t)j * 4 + h] + 1e-16f);
    float4 acc = make_float4(0.f, 0.f, 0.f, 0.f);
    for (unsigned i = 0; i < n; ++i) {
        int q = qlist[beg + i];
        float w = ex[(size_t)q * 4 + h] * inv;
        float4 v = *reinterpret_cast<const float4*>(xq + (size_t)q * DIM + lane * 4);
        acc.x = fmaf(w, v.x, acc.x);
        acc.y = fmaf(w, v.y, acc.y);
        acc.z = fmaf(w, v.z, acc.z);
        acc.w = fmaf(w, v.w, acc.w);
    }
    *reinterpret_cast<float4*>(out + (size_t)j * DIM + lane * 4) = acc;
}

extern "C" void kernel_launch(void* const* d_in, const int* in_sizes, int n_in,
                              void* d_out, int out_size, void* d_ws, size_t ws_size,
                              hipStream_t stream) {
    (void)n_in; (void)out_size; (void)ws_size;
    const float* x_q    = (const float*)d_in[0];
    const float* x_edge = (const float*)d_in[1];
    const float* w_q    = (const float*)d_in[2];
    const float* weight = (const float*)d_in[3];
    const int*   eids   = (const int*)d_in[4];
    const int NQ = in_sizes[0] / DIM;   // 500000
    const int NE = in_sizes[1] / DIM;   // 250000
    float* out = (float*)d_out;

    // workspace layout
    float*    xq        = (float*)d_ws;                       // NQ*256
    float*    gamma     = xq + (size_t)NQ * DIM;              // NQ*4
    float*    logit     = gamma + (size_t)NQ * 4;             // NQ*4 (becomes ex)
    float*    beta      = logit + (size_t)NQ * 4;             // NE*4
    unsigned* segmax    = (unsigned*)(beta + (size_t)NE * 4); // NE*4
    float*    segsum    = (float*)(segmax + (size_t)NE * 4);  // NE*4
    unsigned* counts    = (unsigned*)(segsum + (size_t)NE * 4); // NE
    unsigned* offs      = counts + NE;                        // NE
    unsigned* cursor    = offs + NE;                          // NE
    int*      qlist     = (int*)(cursor + NE);                // NQ
    unsigned* blocksums = (unsigned*)(qlist + NQ);            // <=256

    const int NB = (NE + 1023) / 1024;

    hipMemsetAsync(segmax, 0, (size_t)NE * 4 * sizeof(unsigned), stream);
    hipMemsetAsync(segsum, 0, (size_t)NE * 4 * sizeof(float), stream);
    hipMemsetAsync(counts, 0, (size_t)NE * sizeof(unsigned), stream);

    beta_kernel<<<(NE + 3) / 4, 256, 0, stream>>>(x_edge, weight, beta, NE);
    gemm_gamma_kernel<<<(NQ + BM - 1) / BM, 256, 0, stream>>>(x_q, w_q, weight, xq, gamma, NQ);
    logits_kernel<<<(NQ + 255) / 256, 256, 0, stream>>>(beta, gamma, eids, logit, segmax, counts, NQ);
    exp_kernel<<<(NQ + 255) / 256, 256, 0, stream>>>(logit, eids, segmax, segsum, NQ);
    scan1_kernel<<<NB, 256, 0, stream>>>(counts, offs, blocksums, NE);
    scan2_kernel<<<1, 256, 0, stream>>>(blocksums, NB);
    scan3_kernel<<<NB, 256, 0, stream>>>(offs, blocksums, cursor, NE);
    fill_kernel<<<(NQ + 255) / 256, 256, 0, stream>>>(eids, cursor, qlist, NQ);
    gather_kernel<<<(NE + 3) / 4, 256, 0, stream>>>(logit, segsum, offs, counts, qlist, xq, out, NE);
}

// Round 3
// 807.402 us; speedup vs baseline: 3.5100x; 1.6137x over previous
//
#include <hip/hip_runtime.h>
#include <hip/hip_bf16.h>

#define DIM 256
#define HEADS 4
#define NEG_SLOPE 0.01f

typedef unsigned short u16;
typedef __attribute__((ext_vector_type(8))) short short8;
typedef __attribute__((ext_vector_type(4))) float f32x4;
typedef __attribute__((ext_vector_type(4))) unsigned short u16x4;

// ---- bf16 split helpers (RTN-even, bit ops — no type API dependence) ----
__device__ __forceinline__ u16 f2bf(float f) {
    unsigned u = __float_as_uint(f);
    unsigned r = (u + 0x7fffu + ((u >> 16) & 1u)) >> 16;
    return (u16)r;
}
__device__ __forceinline__ float bf2f(u16 h) {
    return __uint_as_float(((unsigned)h) << 16);
}

// ---- sortable-uint encoding for float atomicMax ----
__device__ __forceinline__ unsigned f2sort(float f) {
    unsigned u = __float_as_uint(f);
    return (u & 0x80000000u) ? ~u : (u | 0x80000000u);
}
__device__ __forceinline__ float sort2f(unsigned s) {
    return (s & 0x80000000u) ? __uint_as_float(s & 0x7fffffffu)
                             : __uint_as_float(~s);
}

// K0: split-transpose w_q (k-major fp32) -> BThi/BTlo (n-major bf16)
__global__ __launch_bounds__(256) void prepb_kernel(const float* __restrict__ B,
                                                    u16* __restrict__ BThi,
                                                    u16* __restrict__ BTlo) {
    int k = blockIdx.x;
    int n = threadIdx.x;
    float f = B[k * 256 + n];
    u16 hi = f2bf(f);
    u16 lo = f2bf(f - bf2f(hi));
    BThi[n * 256 + k] = hi;
    BTlo[n * 256 + k] = lo;
}

// K1: beta[j,h] = sum_{d<64} x_edge[j, h*64+d] * weight[h, d]
__global__ __launch_bounds__(256) void beta_kernel(const float* __restrict__ xe,
                                                   const float* __restrict__ weight,
                                                   float* __restrict__ beta, int NE) {
    int wid = blockIdx.x * 4 + (threadIdx.x >> 6);
    if (wid >= NE) return;
    int lane = threadIdx.x & 63;
    int h = lane >> 4;
    float4 v = *reinterpret_cast<const float4*>(xe + (size_t)wid * DIM + lane * 4);
    float4 w = *reinterpret_cast<const float4*>(weight + h * 128 + (lane & 15) * 4);
    float p = v.x * w.x + v.y * w.y + v.z * w.z + v.w * w.w;
    p += __shfl_xor(p, 1);
    p += __shfl_xor(p, 2);
    p += __shfl_xor(p, 4);
    p += __shfl_xor(p, 8);
    if ((lane & 15) == 0) beta[(size_t)wid * 4 + h] = p;
}

// K2: xq = x_q @ w_q via split-bf16 MFMA (3-product), fused gamma epilogue.
// 512 threads = 8 waves (2 row-halves x 4 col-heads). BM=256, BN=256, BK=32.
#define APITCH 40   // LDS row pitch in bf16 elems (80 B = 20 banks -> <=2-way)
__global__ __launch_bounds__(512, 2) void gemm_gamma_kernel(const float* __restrict__ A,
                                                            const u16* __restrict__ BThi,
                                                            const u16* __restrict__ BTlo,
                                                            const float* __restrict__ weight,
                                                            float* __restrict__ xq_out,
                                                            float* __restrict__ gamma, int NQ) {
    __shared__ u16 Ahi_s[256 * APITCH];
    __shared__ u16 Alo_s[256 * APITCH];
    __shared__ u16 Bhi_s[256 * APITCH];
    __shared__ u16 Blo_s[256 * APITCH];

    const int t = threadIdx.x;
    const int lane = t & 63;
    const int wid = t >> 6;
    const int wr = wid >> 2;       // row half 0/1
    const int wc = wid & 3;        // head / 64-col group
    const int lr = lane & 15;
    const int kg = lane >> 4;
    const long brow = (long)blockIdx.x * 256;

    f32x4 acc[8][4];
#pragma unroll
    for (int m = 0; m < 8; ++m)
#pragma unroll
        for (int n = 0; n < 4; ++n) acc[m][n] = (f32x4){0.f, 0.f, 0.f, 0.f};

    for (int k0 = 0; k0 < DIM; k0 += 32) {
        // stage A tile (256 rows x 32 k) fp32 -> bf16 hi/lo
#pragma unroll
        for (int i = 0; i < 4; ++i) {
            int slot = t + i * 512;
            int row = slot >> 3, c4 = slot & 7;
            long grow = brow + row;
            if (grow >= NQ) grow = NQ - 1;
            float4 v = *reinterpret_cast<const float4*>(A + grow * DIM + k0 + c4 * 4);
            u16x4 hi, lo;
            hi.x = f2bf(v.x); lo.x = f2bf(v.x - bf2f(hi.x));
            hi.y = f2bf(v.y); lo.y = f2bf(v.y - bf2f(hi.y));
            hi.z = f2bf(v.z); lo.z = f2bf(v.z - bf2f(hi.z));
            hi.w = f2bf(v.w); lo.w = f2bf(v.w - bf2f(hi.w));
            *reinterpret_cast<u16x4*>(&Ahi_s[row * APITCH + c4 * 4]) = hi;
            *reinterpret_cast<u16x4*>(&Alo_s[row * APITCH + c4 * 4]) = lo;
        }
        // stage B tile (256 n x 32 k) bf16 copy from pre-transposed hi/lo
#pragma unroll
        for (int i = 0; i < 2; ++i) {
            int slot = t + i * 512;
            int n = slot >> 2, c = slot & 3;
            uint4 vh = *reinterpret_cast<const uint4*>(BThi + n * 256 + k0 + c * 8);
            uint4 vl = *reinterpret_cast<const uint4*>(BTlo + n * 256 + k0 + c * 8);
            *reinterpret_cast<uint4*>(&Bhi_s[n * APITCH + c * 8]) = vh;
            *reinterpret_cast<uint4*>(&Blo_s[n * APITCH + c * 8]) = vl;
        }
        __syncthreads();

        short8 bh[4], bl[4];
#pragma unroll
        for (int n = 0; n < 4; ++n) {
            int nn = wc * 64 + n * 16 + lr;
            bh[n] = *reinterpret_cast<const short8*>(&Bhi_s[nn * APITCH + kg * 8]);
            bl[n] = *reinterpret_cast<const short8*>(&Blo_s[nn * APITCH + kg * 8]);
        }
#pragma unroll
        for (int m = 0; m < 8; ++m) {
            int rr = wr * 128 + m * 16 + lr;
            short8 ah = *reinterpret_cast<const short8*>(&Ahi_s[rr * APITCH + kg * 8]);
            short8 al = *reinterpret_cast<const short8*>(&Alo_s[rr * APITCH + kg * 8]);
#pragma unroll
            for (int n = 0; n < 4; ++n) {
                acc[m][n] = __builtin_amdgcn_mfma_f32_16x16x32_bf16(ah, bh[n], acc[m][n], 0, 0, 0);
                acc[m][n] = __builtin_amdgcn_mfma_f32_16x16x32_bf16(ah, bl[n], acc[m][n], 0, 0, 0);
                acc[m][n] = __builtin_amdgcn_mfma_f32_16x16x32_bf16(al, bh[n], acc[m][n], 0, 0, 0);
            }
        }
        __syncthreads();
    }

    // epilogue: xq stores + fused per-head gamma
    float wv[4];
#pragma unroll
    for (int n = 0; n < 4; ++n) wv[n] = weight[wc * 128 + 64 + n * 16 + lr];

#pragma unroll
    for (int m = 0; m < 8; ++m) {
        long rowm = brow + wr * 128 + m * 16 + kg * 4;
#pragma unroll
        for (int r = 0; r < 4; ++r) {
            long row = rowm + r;
            bool ok = row < NQ;
            float p = 0.f;
#pragma unroll
            for (int n = 0; n < 4; ++n) {
                float v = acc[m][n][r];
                if (ok) xq_out[row * DIM + wc * 64 + n * 16 + lr] = v;
                p = fmaf(v, wv[n], p);
            }
            p += __shfl_xor(p, 1);
            p += __shfl_xor(p, 2);
            p += __shfl_xor(p, 4);
            p += __shfl_xor(p, 8);
            if (ok && lr == 0) gamma[row * 4 + wc] = p;
        }
    }
}

// K3: logit = leaky_relu(beta[eid] + gamma); atomicMax segmax; histogram counts
__global__ __launch_bounds__(256) void logits_kernel(const float* __restrict__ beta,
                                                     const float* __restrict__ gamma,
                                                     const int* __restrict__ eids,
                                                     float* __restrict__ logit,
                                                     unsigned* __restrict__ segmax,
                                                     unsigned* __restrict__ counts, int NQ) {
    int e = blockIdx.x * blockDim.x + threadIdx.x;
    if (e >= NQ) return;
    int j = eids[e];
    float4 g = *reinterpret_cast<const float4*>(gamma + (size_t)e * 4);
    float4 b = *reinterpret_cast<const float4*>(beta + (size_t)j * 4);
    float l[4] = {b.x + g.x, b.y + g.y, b.z + g.z, b.w + g.w};
#pragma unroll
    for (int h = 0; h < 4; ++h) {
        l[h] = l[h] > 0.f ? l[h] : NEG_SLOPE * l[h];
        atomicMax(&segmax[(size_t)j * 4 + h], f2sort(l[h]));
    }
    atomicAdd(&counts[j], 1u);
    *reinterpret_cast<float4*>(logit + (size_t)e * 4) = make_float4(l[0], l[1], l[2], l[3]);
}

// K4: ex = exp(logit - segmax[eid]); atomicAdd segsum (in place over logit)
__global__ __launch_bounds__(256) void exp_kernel(float* __restrict__ logit,
                                                  const int* __restrict__ eids,
                                                  const unsigned* __restrict__ segmax,
                                                  float* __restrict__ segsum, int NQ) {
    int e = blockIdx.x * blockDim.x + threadIdx.x;
    if (e >= NQ) return;
    int j = eids[e];
    float4 l = *reinterpret_cast<const float4*>(logit + (size_t)e * 4);
    uint4 m = *reinterpret_cast<const uint4*>(segmax + (size_t)j * 4);
    float ex[4] = {__expf(l.x - sort2f(m.x)), __expf(l.y - sort2f(m.y)),
                   __expf(l.z - sort2f(m.z)), __expf(l.w - sort2f(m.w))};
    *reinterpret_cast<float4*>(logit + (size_t)e * 4) = make_float4(ex[0], ex[1], ex[2], ex[3]);
#pragma unroll
    for (int h = 0; h < 4; ++h) atomicAdd(&segsum[(size_t)j * 4 + h], ex[h]);
}

// ---- CSR build ----
__global__ __launch_bounds__(256) void scan1_kernel(const unsigned* __restrict__ counts,
                                                    unsigned* __restrict__ offs,
                                                    unsigned* __restrict__ blocksums, int NE) {
    __shared__ unsigned s[256];
    int t = threadIdx.x;
    int base = blockIdx.x * 1024 + t * 4;
    unsigned v[4], sum = 0;
#pragma unroll
    for (int i = 0; i < 4; ++i) {
        v[i] = (base + i < NE) ? counts[base + i] : 0u;
        sum += v[i];
    }
    s[t] = sum;
    __syncthreads();
    for (int off = 1; off < 256; off <<= 1) {
        unsigned y = (t >= off) ? s[t - off] : 0u;
        __syncthreads();
        s[t] += y;
        __syncthreads();
    }
    unsigned excl = s[t] - sum;
#pragma unroll
    for (int i = 0; i < 4; ++i) {
        if (base + i < NE) offs[base + i] = excl;
        excl += v[i];
    }
    if (t == 255) blocksums[blockIdx.x] = s[255];
}

__global__ __launch_bounds__(256) void scan2_kernel(unsigned* __restrict__ blocksums, int NB) {
    __shared__ unsigned s[256];
    int t = threadIdx.x;
    unsigned v = (t < NB) ? blocksums[t] : 0u;
    s[t] = v;
    __syncthreads();
    for (int off = 1; off < 256; off <<= 1) {
        unsigned y = (t >= off) ? s[t - off] : 0u;
        __syncthreads();
        s[t] += y;
        __syncthreads();
    }
    if (t < NB) blocksums[t] = s[t] - v;
}

__global__ __launch_bounds__(256) void scan3_kernel(unsigned* __restrict__ offs,
                                                    const unsigned* __restrict__ blocksums,
                                                    unsigned* __restrict__ cursor, int NE) {
    int t = threadIdx.x;
    int base = blockIdx.x * 1024 + t * 4;
    unsigned add = blocksums[blockIdx.x];
#pragma unroll
    for (int i = 0; i < 4; ++i) {
        if (base + i < NE) {
            unsigned o = offs[base + i] + add;
            offs[base + i] = o;
            cursor[base + i] = o;
        }
    }
}

__global__ __launch_bounds__(256) void fill_kernel(const int* __restrict__ eids,
                                                   unsigned* __restrict__ cursor,
                                                   int* __restrict__ qlist, int NQ) {
    int e = blockIdx.x * blockDim.x + threadIdx.x;
    if (e >= NQ) return;
    int j = eids[e];
    unsigned pos = atomicAdd(&cursor[j], 1u);
    qlist[pos] = e;
}

// gather: out[j,:] = sum_{q in seg(j)} (ex[q,h]/(segsum[j,h]+eps)) * xq[q,:]
__global__ __launch_bounds__(256) void gather_kernel(const float* __restrict__ ex,
                                                     const float* __restrict__ segsum,
                                                     const unsigned* __restrict__ offs,
                                                     const unsigned* __restrict__ counts,
                                                     const int* __restrict__ qlist,
                                                     const float* __restrict__ xq,
                                                     float* __restrict__ out, int NE) {
    int j = blockIdx.x * 4 + (threadIdx.x >> 6);
    if (j >= NE) return;
    int lane = threadIdx.x & 63;
    int h = lane >> 4;
    unsigned beg = offs[j];
    unsigned n = counts[j];
    float inv = 1.0f / (segsum[(size_t)j * 4 + h] + 1e-16f);
    float4 acc = make_float4(0.f, 0.f, 0.f, 0.f);
    for (unsigned i = 0; i < n; ++i) {
        int q = qlist[beg + i];
        float w = ex[(size_t)q * 4 + h] * inv;
        float4 v = *reinterpret_cast<const float4*>(xq + (size_t)q * DIM + lane * 4);
        acc.x = fmaf(w, v.x, acc.x);
        acc.y = fmaf(w, v.y, acc.y);
        acc.z = fmaf(w, v.z, acc.z);
        acc.w = fmaf(w, v.w, acc.w);
    }
    *reinterpret_cast<float4*>(out + (size_t)j * DIM + lane * 4) = acc;
}

extern "C" void kernel_launch(void* const* d_in, const int* in_sizes, int n_in,
                              void* d_out, int out_size, void* d_ws, size_t ws_size,
                              hipStream_t stream) {
    (void)n_in; (void)out_size; (void)ws_size;
    const float* x_q    = (const float*)d_in[0];
    const float* x_edge = (const float*)d_in[1];
    const float* w_q    = (const float*)d_in[2];
    const float* weight = (const float*)d_in[3];
    const int*   eids   = (const int*)d_in[4];
    const int NQ = in_sizes[0] / DIM;   // 500000
    const int NE = in_sizes[1] / DIM;   // 250000
    float* out = (float*)d_out;

    // workspace layout
    float*    xq        = (float*)d_ws;                         // NQ*256
    float*    gamma     = xq + (size_t)NQ * DIM;                // NQ*4
    float*    logit     = gamma + (size_t)NQ * 4;               // NQ*4 (becomes ex)
    float*    beta      = logit + (size_t)NQ * 4;               // NE*4
    unsigned* segmax    = (unsigned*)(beta + (size_t)NE * 4);   // NE*4
    float*    segsum    = (float*)(segmax + (size_t)NE * 4);    // NE*4
    unsigned* counts    = (unsigned*)(segsum + (size_t)NE * 4); // NE
    unsigned* offs      = counts + NE;                          // NE
    unsigned* cursor    = offs + NE;                            // NE
    int*      qlist     = (int*)(cursor + NE);                  // NQ
    unsigned* blocksums = (unsigned*)(qlist + NQ);              // 256
    u16*      BThi      = (u16*)(blocksums + 256);              // 256*256
    u16*      BTlo      = BThi + 256 * 256;                     // 256*256

    const int NB = (NE + 1023) / 1024;

    hipMemsetAsync(segmax, 0, (size_t)NE * 4 * sizeof(unsigned), stream);
    hipMemsetAsync(segsum, 0, (size_t)NE * 4 * sizeof(float), stream);
    hipMemsetAsync(counts, 0, (size_t)NE * sizeof(unsigned), stream);

    prepb_kernel<<<256, 256, 0, stream>>>(w_q, BThi, BTlo);
    beta_kernel<<<(NE + 3) / 4, 256, 0, stream>>>(x_edge, weight, beta, NE);
    gemm_gamma_kernel<<<(NQ + 255) / 256, 512, 0, stream>>>(x_q, BThi, BTlo, weight, xq, gamma, NQ);
    logits_kernel<<<(NQ + 255) / 256, 256, 0, stream>>>(beta, gamma, eids, logit, segmax, counts, NQ);
    exp_kernel<<<(NQ + 255) / 256, 256, 0, stream>>>(logit, eids, segmax, segsum, NQ);
    scan1_kernel<<<NB, 256, 0, stream>>>(counts, offs, blocksums, NE);
    scan2_kernel<<<1, 256, 0, stream>>>(blocksums, NB);
    scan3_kernel<<<NB, 256, 0, stream>>>(offs, blocksums, cursor, NE);
    fill_kernel<<<(NQ + 255) / 256, 256, 0, stream>>>(eids, cursor, qlist, NQ);
    gather_kernel<<<(NE + 3) / 4, 256, 0, stream>>>(logit, segsum, offs, counts, qlist, xq, out, NE);
}